// Round 10
// baseline (228.991 us; speedup 1.0000x reference)
//
#include <hip/hip_runtime.h>
#include <hip/hip_fp16.h>
#include <cstdint>

// 2-layer GAT, PyG GATConv semantics (concat heads, self-loops, segment softmax).
// R10: GEMMs moved to MFMA (v_mfma_f32_16x16x32_f16, fp16 in / f32 acc).
// R9 showed the f32 VALU gemm is structurally capped (gemm<64> == gemm<256> ==
// 59us, VALUBusy 48%, occupancy 29%). Layer-2 input xbuf stored fp16 by
// node_agg (same quantization count as stage-time cvt). W pre-transposed to
// fp16 W^T by a prep kernel; x staged to LDS fp16 per 64-k chunk.
// Fragment layouts (verified m89/m91): A: row=lane&15, k=(lane>>4)*8+j;
// B: col=lane&15, same k; D: col=lane&15, row=(lane>>4)*4+reg.
// fp16 h gather table (R8), channel-paired node_agg (R9), CSR build (R7).
// Softmax max-subtraction omitted: shift-invariant, |e| <= ~10 so exp() safe in f32.

#define CH 4096    // edges per block in hist/place
#define MAXB 512   // LDS bucket array size (NBUCK = ceil(n/256) = 391)
#define SCAP 6144  // pass-2 LDS sort capacity (mean 4352, sigma ~66 -> never hit)

using f16x8 = __attribute__((ext_vector_type(8))) _Float16;
using f16x4 = __attribute__((ext_vector_type(4))) _Float16;
using f32x4 = __attribute__((ext_vector_type(4))) float;

__device__ __forceinline__ float lrelu(float v) { return fmaxf(v, 0.2f * v); }

__global__ void ifill_kernel(int* __restrict__ p, int v, int n) {
  int i = blockIdx.x * blockDim.x + threadIdx.x;
  if (i < n) p[i] = v;
}

// W [K][64] f32 -> WT [64][K] fp16 (tiny: 16K/4K elems).
__global__ void wprep_kernel(const float* __restrict__ W, ushort* __restrict__ WT,
                             int K) {
  int i = blockIdx.x * 256 + threadIdx.x;
  if (i < K * 64) {
    int k = i >> 6, nn = i & 63;
    WT[nn * K + k] = __half_as_ushort(__float2half_rn(W[i]));
  }
}

// k1: per-block LDS histogram of dst buckets -> global bucket_cnt.
__global__ __launch_bounds__(256) void bucket_hist(const int* __restrict__ edst,
                                                   int E, int nbuck,
                                                   int* __restrict__ bucket_cnt) {
  __shared__ int hist[MAXB];
  const int t = threadIdx.x;
  for (int j = t; j < MAXB; j += 256) hist[j] = 0;
  __syncthreads();
  const int base = blockIdx.x * CH;
#pragma unroll
  for (int k = 0; k < CH / 256; ++k) {
    int e = base + k * 256 + t;
    if (e < E) atomicAdd(&hist[edst[e] >> 8], 1);
  }
  __syncthreads();
  for (int j = t; j < nbuck; j += 256) {
    int c = hist[j];
    if (c) atomicAdd(&bucket_cnt[j], c);
  }
}

// k2: single-WG exclusive scan of bucket_cnt -> bucket_base (+ total) + cursor.
__global__ __launch_bounds__(512) void bucket_scan(const int* __restrict__ bucket_cnt,
                                                   int* __restrict__ bucket_base,
                                                   int* __restrict__ bucket_cursor,
                                                   int nbuck) {
  __shared__ int part[512];
  const int t = threadIdx.x;
  int v = (t < nbuck) ? bucket_cnt[t] : 0;
  part[t] = v;
  __syncthreads();
  for (int off = 1; off < 512; off <<= 1) {
    int u = (t >= off) ? part[t - off] : 0;
    __syncthreads();
    part[t] += u;
    __syncthreads();
  }
  int ex = part[t] - v;  // exclusive
  if (t <= nbuck) {      // t==nbuck writes total E
    int w = (t < nbuck) ? ex : part[nbuck - 1];
    bucket_base[t] = w;
    if (t < nbuck) bucket_cursor[t] = w;
  }
}

// k3: place packed edges into bucket regions. Per-block LDS hist -> one global
// reservation per (block,bucket) -> per-edge LDS rank -> scattered u32 write.
__global__ __launch_bounds__(256) void place_kernel(const int* __restrict__ esrc,
                                                    const int* __restrict__ edst,
                                                    int E, int nbuck,
                                                    int* __restrict__ bucket_cursor,
                                                    unsigned int* __restrict__ pairs) {
  __shared__ int hist[MAXB];
  __shared__ int gbase[MAXB];
  __shared__ int rcnt[MAXB];
  const int t = threadIdx.x;
  for (int j = t; j < MAXB; j += 256) { hist[j] = 0; rcnt[j] = 0; }
  __syncthreads();
  const int base = blockIdx.x * CH;
  int b_[CH / 256];
  unsigned int p_[CH / 256];
#pragma unroll
  for (int k = 0; k < CH / 256; ++k) {
    int e = base + k * 256 + t;
    if (e < E) {
      int d = edst[e];
      int s = esrc[e];
      b_[k] = d >> 8;
      p_[k] = ((unsigned int)s << 8) | (unsigned int)(d & 255);
      atomicAdd(&hist[b_[k]], 1);
    } else {
      b_[k] = -1;
    }
  }
  __syncthreads();
  for (int j = t; j < nbuck; j += 256) {
    int c = hist[j];
    gbase[j] = c ? atomicAdd(&bucket_cursor[j], c) : 0;
  }
  __syncthreads();
#pragma unroll
  for (int k = 0; k < CH / 256; ++k) {
    if (b_[k] >= 0) {
      int r = atomicAdd(&rcnt[b_[k]], 1);
      pairs[gbase[b_[k]] + r] = p_[k];
    }
  }
}

// k4: one block per bucket. LDS counting-sort by local dst, inject self-loops,
// emit ccol segment + start/end coalesced.
__global__ __launch_bounds__(256) void bucket_build(
    const unsigned int* __restrict__ pairs, const int* __restrict__ bucket_base,
    int* __restrict__ ccol, int* __restrict__ start, int* __restrict__ endp,
    int n) {
  __shared__ int cnt[256];
  __shared__ int ls[256];
  __shared__ int csave[256];
  __shared__ int part[256];
  __shared__ int sorted[SCAP];
  const int t = threadIdx.x;
  const int b = blockIdx.x;
  const int d0 = b << 8;
  const int DR = min(256, n - d0);
  const int in_base = bucket_base[b];
  const int nloc = bucket_base[b + 1] - in_base;
  const int out_base = in_base + d0;  // self-loops of earlier (full) buckets = d0

  cnt[t] = (t < DR) ? 1 : 0;  // 1 = self-loop
  __syncthreads();
  for (int i = t; i < nloc; i += 256)
    atomicAdd(&cnt[pairs[in_base + i] & 255u], 1);
  __syncthreads();
  int c = cnt[t];
  csave[t] = c;
  part[t] = c;
  __syncthreads();
#pragma unroll
  for (int off = 1; off < 256; off <<= 1) {
    int u = (t >= off) ? part[t - off] : 0;
    __syncthreads();
    part[t] += u;
    __syncthreads();
  }
  ls[t] = part[t] - c;  // exclusive local start
  __syncthreads();
  if (t < DR) {
    int s = out_base + ls[t];
    start[d0 + t] = s;
    endp[d0 + t] = s + csave[t];
    sorted[ls[t]] = d0 + t;  // self-loop src
    cnt[t] = 1;              // reuse as rank counter, slot 0 taken
  }
  __syncthreads();
  for (int i = t; i < nloc; i += 256) {
    unsigned int p = pairs[in_base + i];
    int j = (int)(p & 255u);
    int r = atomicAdd(&cnt[j], 1);
    int pos = ls[j] + r;
    if (pos < SCAP) sorted[pos] = (int)(p >> 8);
  }
  __syncthreads();
  int tot = nloc + DR;
  if (tot > SCAP) tot = SCAP;
  for (int i = t; i < tot; i += 256) ccol[out_base + i] = sorted[i];
}

// MFMA GEMM: h[n][64] = x[n][K] @ W[K][64], h stored fp16; per-head att dots.
// Block = 64 rows; wave w owns rows w*16..+15, 4 col-tiles (== heads) of 16.
// WT fp16 staged once; x staged per 64-k chunk (f32->fp16 cvt or fp16 copy).
template <int K, bool XHALF>
__global__ __launch_bounds__(256) void gemm_mfma(
    const void* __restrict__ xin, const ushort* __restrict__ wt,
    const float* __restrict__ att_src, const float* __restrict__ att_dst,
    __half* __restrict__ h, float* __restrict__ as_, float* __restrict__ ad_,
    int n) {
  constexpr int WS = K + 8;           // wsh row stride (halfs)
  __shared__ _Float16 wsh[64 * WS];   // W^T [col][k]
  __shared__ _Float16 xsh[64 * 72];   // x chunk [row][k], stride 72
  const int tid = threadIdx.x;
  const int w = tid >> 6;
  const int lane = tid & 63;
  const int lr = lane & 15;   // A row / B col within tile
  const int kg = lane >> 4;   // k-group
  const int row0 = blockIdx.x * 64;

  {  // stage W^T: 64*K halfs, coalesced ushort4
    const ushort4* src = (const ushort4*)wt;
    for (int i4 = tid; i4 < 64 * K / 4; i4 += 256) {
      int nr = i4 / (K / 4);
      int kc = i4 % (K / 4);
      *(ushort4*)&wsh[nr * WS + kc * 4] = src[i4];
    }
  }

  f32x4 acc[4] = {};
  const int tr = tid >> 2;         // staging row
  const int tc = (tid & 3) * 16;   // staging col base (16 elems)
  int rr = row0 + tr;
  if (rr > n - 1) rr = n - 1;      // clamp tail (results discarded by guards)

  for (int c = 0; c < K; c += 64) {
    __syncthreads();  // W^T staged / previous chunk consumed
    if constexpr (!XHALF) {
      const float* xp = (const float*)xin + (long long)rr * K + c + tc;
#pragma unroll
      for (int j = 0; j < 4; ++j) {
        float4 v = *(const float4*)(xp + j * 4);
        f16x4 hv;
        hv[0] = (_Float16)v.x; hv[1] = (_Float16)v.y;
        hv[2] = (_Float16)v.z; hv[3] = (_Float16)v.w;
        *(f16x4*)&xsh[tr * 72 + tc + j * 4] = hv;
      }
    } else {
      const ushort* xp = (const ushort*)xin + (long long)rr * K + c + tc;
#pragma unroll
      for (int j = 0; j < 4; ++j)
        *(ushort4*)&xsh[tr * 72 + tc + j * 4] = *(const ushort4*)(xp + j * 4);
    }
    __syncthreads();
#pragma unroll
    for (int ks = 0; ks < 64; ks += 32) {
      f16x8 a = *(const f16x8*)&xsh[(w * 16 + lr) * 72 + ks + kg * 8];
#pragma unroll
      for (int ct = 0; ct < 4; ++ct) {
        f16x8 b = *(const f16x8*)&wsh[(ct * 16 + lr) * WS + c + ks + kg * 8];
        acc[ct] = __builtin_amdgcn_mfma_f32_16x16x32_f16(a, b, acc[ct], 0, 0, 0);
      }
    }
  }

  // Epilogue: D[row=(lane>>4)*4+r][col=ct*16+lr]. h fp16 store + att dots
  // (head == col-tile ct); reduce over the 16 lanes holding a row.
  const int wrow = row0 + w * 16 + kg * 4;
#pragma unroll
  for (int ct = 0; ct < 4; ++ct) {
    const float as0 = att_src[ct * 16 + lr];
    const float ad0 = att_dst[ct * 16 + lr];
#pragma unroll
    for (int r = 0; r < 4; ++r) {
      const int row = wrow + r;
      const float v = acc[ct][r];
      if (row < n) h[(long long)row * 64 + ct * 16 + lr] = __float2half_rn(v);
      float s = v * as0, d = v * ad0;
      s += __shfl_xor(s, 1); s += __shfl_xor(s, 2);
      s += __shfl_xor(s, 4); s += __shfl_xor(s, 8);
      d += __shfl_xor(d, 1); d += __shfl_xor(d, 2);
      d += __shfl_xor(d, 4); d += __shfl_xor(d, 8);
      if (lr == 0 && row < n) {
        as_[row * 4 + ct] = s;
        ad_[row * 4 + ct] = d;
      }
    }
  }
}

// Half-wave (32 lanes) per dst node, 2 nodes/wave; lane covers 2 channels via
// __half2. mode 1: relu + fp16 out (layer-2 GEMM input); mode 0: f32 out.
__global__ __launch_bounds__(256) void node_agg_kernel(
    const int* __restrict__ ccol, const int* __restrict__ start,
    const int* __restrict__ endp,
    const float* __restrict__ as_, const float* __restrict__ ad_,
    const __half2* __restrict__ h2, const float* __restrict__ bias,
    float* __restrict__ fout, __half2* __restrict__ hout, int n, int mode) {
  const int node = blockIdx.x * 8 + (threadIdx.x >> 5);
  if (node >= n) return;
  const int hl = threadIdx.x & 31;  // half-lane: channels 2hl, 2hl+1
  const int hh = hl >> 3;           // head (8 half-lanes/head)
  const float adv = ad_[node * 4 + hh];
  const int s0i = start[node];
  const int d = endp[node] - s0i;
  const int* cp = ccol + s0i;
  float ax = 0.f, ay = 0.f, den = 0.f;
  int i = 0;
  for (; i + 4 <= d; i += 4) {  // 4x unroll for memory-level parallelism
    int s0 = cp[i], s1 = cp[i + 1], s2 = cp[i + 2], s3 = cp[i + 3];
    float p0 = __expf(lrelu(as_[s0 * 4 + hh] + adv));
    float p1 = __expf(lrelu(as_[s1 * 4 + hh] + adv));
    float p2 = __expf(lrelu(as_[s2 * 4 + hh] + adv));
    float p3 = __expf(lrelu(as_[s3 * 4 + hh] + adv));
    float2 h0 = __half22float2(h2[s0 * 32 + hl]);
    float2 h1 = __half22float2(h2[s1 * 32 + hl]);
    float2 h2v = __half22float2(h2[s2 * 32 + hl]);
    float2 h3 = __half22float2(h2[s3 * 32 + hl]);
    den += (p0 + p1) + (p2 + p3);
    ax = fmaf(p0, h0.x, ax); ay = fmaf(p0, h0.y, ay);
    ax = fmaf(p1, h1.x, ax); ay = fmaf(p1, h1.y, ay);
    ax = fmaf(p2, h2v.x, ax); ay = fmaf(p2, h2v.y, ay);
    ax = fmaf(p3, h3.x, ax); ay = fmaf(p3, h3.y, ay);
  }
  for (; i < d; ++i) {
    int s0 = cp[i];
    float p0 = __expf(lrelu(as_[s0 * 4 + hh] + adv));
    float2 h0 = __half22float2(h2[s0 * 32 + hl]);
    den += p0;
    ax = fmaf(p0, h0.x, ax); ay = fmaf(p0, h0.y, ay);
  }
  const float inv = 1.0f / (den + 1e-16f);
  float vx = ax * inv + bias[hl * 2];
  float vy = ay * inv + bias[hl * 2 + 1];
  if (mode == 1) {
    vx = fmaxf(vx, 0.f);
    vy = fmaxf(vy, 0.f);
    hout[node * 32 + hl] = __floats2half2_rn(vx, vy);
  } else {
    *(float2*)(fout + node * 64 + hl * 2) = make_float2(vx, vy);
  }
}

extern "C" void kernel_launch(void* const* d_in, const int* in_sizes, int n_in,
                              void* d_out, int out_size, void* d_ws, size_t ws_size,
                              hipStream_t stream) {
  const float* x = (const float*)d_in[0];
  const int* ei = (const int*)d_in[1];
  const float* W1 = (const float*)d_in[2];
  const float* att_s1 = (const float*)d_in[3];
  const float* att_d1 = (const float*)d_in[4];
  const float* b1 = (const float*)d_in[5];
  const float* W2 = (const float*)d_in[6];
  const float* att_s2 = (const float*)d_in[7];
  const float* att_d2 = (const float*)d_in[8];
  const float* b2 = (const float*)d_in[9];

  const int n = in_sizes[0] / 256;  // 100000
  const int E = in_sizes[1] / 2;    // 1600000
  const int* esrc = ei;
  const int* edst = ei + E;
  const int nbuck = (n + 255) >> 8;  // 391

  float* wsf = (float*)d_ws;
  __half* hbuf = (__half*)wsf;                  // [n*64] fp16 h (region: n*64 floats)
  float* xbuf = wsf + (long long)n * 64;        // [n*64] region; holds fp16 layer-2 input
  float* as_ = xbuf + (long long)n * 64;        // [n*4]
  float* ad_ = as_ + (long long)n * 4;          // [n*4]
  int* bucket_cnt = (int*)(ad_ + (long long)n * 4);  // [MAXB]
  int* bucket_base = bucket_cnt + MAXB;         // [MAXB+1]
  int* bucket_cursor = bucket_base + MAXB + 1;  // [MAXB]
  int* start = bucket_cursor + MAXB;            // [n]
  int* endp = start + n;                        // [n]
  unsigned int* pairs = (unsigned int*)(endp + n);  // [E]
  int* ccol = (int*)(pairs + E);                // [E+n]
  ushort* wt1 = (ushort*)(((uintptr_t)(ccol + E + n) + 15) & ~(uintptr_t)15);  // [64*256]
  ushort* wt2 = wt1 + 64 * 256;                 // [64*64]
  float* out = (float*)d_out;

  const int ebk = (E + CH - 1) / CH;  // 391 edge-chunk blocks
  const int gb = (n + 63) / 64;
  const int nb = (n + 7) / 8;  // 8 nodes per 256-thread block (2 per wave)

  // ---- prep: W -> W^T fp16 ----
  wprep_kernel<<<(256 * 64 + 255) / 256, 256, 0, stream>>>(W1, wt1, 256);
  wprep_kernel<<<(64 * 64 + 255) / 256, 256, 0, stream>>>(W2, wt2, 64);

  // ---- CSR bucket build (shared by both layers) ----
  ifill_kernel<<<(MAXB + 255) / 256, 256, 0, stream>>>(bucket_cnt, 0, MAXB);
  bucket_hist<<<ebk, 256, 0, stream>>>(edst, E, nbuck, bucket_cnt);
  bucket_scan<<<1, 512, 0, stream>>>(bucket_cnt, bucket_base, bucket_cursor, nbuck);
  place_kernel<<<ebk, 256, 0, stream>>>(esrc, edst, E, nbuck, bucket_cursor, pairs);
  bucket_build<<<nbuck, 256, 0, stream>>>(pairs, bucket_base, ccol, start, endp, n);

  // ---- layer 1 ----
  gemm_mfma<256, false><<<gb, 256, 0, stream>>>(x, wt1, att_s1, att_d1,
                                                hbuf, as_, ad_, n);
  node_agg_kernel<<<nb, 256, 0, stream>>>(ccol, start, endp, as_, ad_,
                                          (const __half2*)hbuf, b1,
                                          nullptr, (__half2*)xbuf, n, 1);

  // ---- layer 2 ----
  gemm_mfma<64, true><<<gb, 256, 0, stream>>>(xbuf, wt2, att_s2, att_d2,
                                              hbuf, as_, ad_, n);
  node_agg_kernel<<<nb, 256, 0, stream>>>(ccol, start, endp, as_, ad_,
                                          (const __half2*)hbuf, b2,
                                          out, nullptr, n, 0);
}

// Round 11
// 219.307 us; speedup vs baseline: 1.0442x; 1.0442x over previous
//
#include <hip/hip_runtime.h>
#include <hip/hip_fp16.h>
#include <cstdint>

// 2-layer GAT, PyG GATConv semantics (concat heads, self-loops, segment softmax).
// R11: MFMA GEMM restructured — A fragments loaded DIRECTLY global->register
// (16B/lane, 16 rows x 64B coalesced segments per instruction), W^T staged in
// LDS once (single barrier per block), K-loop fully unrolled with NO barriers.
// R10's version was latency-bound (MfmaUtil 1.8%, VALUBusy 7.4%, 9 barriers/
// block forcing a staging drain per 64-k chunk; gemm<64> == gemm<256> == 67us).
// Fragments (verified): A row=lane&15, k=(lane>>4)*8+j; B col=lane&15 same k;
// D col=lane&15, row=(lane>>4)*4+reg.
// fp16 h gather table (R8), channel-paired node_agg (R9), CSR build (R7).
// Softmax max-subtraction omitted: shift-invariant, |e| <= ~10 so exp() safe in f32.

#define CH 4096    // edges per block in hist/place
#define MAXB 512   // LDS bucket array size (NBUCK = ceil(n/256) = 391)
#define SCAP 6144  // pass-2 LDS sort capacity (mean 4352, sigma ~66 -> never hit)

using f16x8 = __attribute__((ext_vector_type(8))) _Float16;
using f16x4 = __attribute__((ext_vector_type(4))) _Float16;
using f32x4 = __attribute__((ext_vector_type(4))) float;

__device__ __forceinline__ float lrelu(float v) { return fmaxf(v, 0.2f * v); }

__global__ void ifill_kernel(int* __restrict__ p, int v, int n) {
  int i = blockIdx.x * blockDim.x + threadIdx.x;
  if (i < n) p[i] = v;
}

// W [K][64] f32 -> WT [64][K] fp16 (tiny: 16K/4K elems).
__global__ void wprep_kernel(const float* __restrict__ W, ushort* __restrict__ WT,
                             int K) {
  int i = blockIdx.x * 256 + threadIdx.x;
  if (i < K * 64) {
    int k = i >> 6, nn = i & 63;
    WT[nn * K + k] = __half_as_ushort(__float2half_rn(W[i]));
  }
}

// k1: per-block LDS histogram of dst buckets -> global bucket_cnt.
__global__ __launch_bounds__(256) void bucket_hist(const int* __restrict__ edst,
                                                   int E, int nbuck,
                                                   int* __restrict__ bucket_cnt) {
  __shared__ int hist[MAXB];
  const int t = threadIdx.x;
  for (int j = t; j < MAXB; j += 256) hist[j] = 0;
  __syncthreads();
  const int base = blockIdx.x * CH;
#pragma unroll
  for (int k = 0; k < CH / 256; ++k) {
    int e = base + k * 256 + t;
    if (e < E) atomicAdd(&hist[edst[e] >> 8], 1);
  }
  __syncthreads();
  for (int j = t; j < nbuck; j += 256) {
    int c = hist[j];
    if (c) atomicAdd(&bucket_cnt[j], c);
  }
}

// k2: single-WG exclusive scan of bucket_cnt -> bucket_base (+ total) + cursor.
__global__ __launch_bounds__(512) void bucket_scan(const int* __restrict__ bucket_cnt,
                                                   int* __restrict__ bucket_base,
                                                   int* __restrict__ bucket_cursor,
                                                   int nbuck) {
  __shared__ int part[512];
  const int t = threadIdx.x;
  int v = (t < nbuck) ? bucket_cnt[t] : 0;
  part[t] = v;
  __syncthreads();
  for (int off = 1; off < 512; off <<= 1) {
    int u = (t >= off) ? part[t - off] : 0;
    __syncthreads();
    part[t] += u;
    __syncthreads();
  }
  int ex = part[t] - v;  // exclusive
  if (t <= nbuck) {      // t==nbuck writes total E
    int w = (t < nbuck) ? ex : part[nbuck - 1];
    bucket_base[t] = w;
    if (t < nbuck) bucket_cursor[t] = w;
  }
}

// k3: place packed edges into bucket regions. Per-block LDS hist -> one global
// reservation per (block,bucket) -> per-edge LDS rank -> scattered u32 write.
__global__ __launch_bounds__(256) void place_kernel(const int* __restrict__ esrc,
                                                    const int* __restrict__ edst,
                                                    int E, int nbuck,
                                                    int* __restrict__ bucket_cursor,
                                                    unsigned int* __restrict__ pairs) {
  __shared__ int hist[MAXB];
  __shared__ int gbase[MAXB];
  __shared__ int rcnt[MAXB];
  const int t = threadIdx.x;
  for (int j = t; j < MAXB; j += 256) { hist[j] = 0; rcnt[j] = 0; }
  __syncthreads();
  const int base = blockIdx.x * CH;
  int b_[CH / 256];
  unsigned int p_[CH / 256];
#pragma unroll
  for (int k = 0; k < CH / 256; ++k) {
    int e = base + k * 256 + t;
    if (e < E) {
      int d = edst[e];
      int s = esrc[e];
      b_[k] = d >> 8;
      p_[k] = ((unsigned int)s << 8) | (unsigned int)(d & 255);
      atomicAdd(&hist[b_[k]], 1);
    } else {
      b_[k] = -1;
    }
  }
  __syncthreads();
  for (int j = t; j < nbuck; j += 256) {
    int c = hist[j];
    gbase[j] = c ? atomicAdd(&bucket_cursor[j], c) : 0;
  }
  __syncthreads();
#pragma unroll
  for (int k = 0; k < CH / 256; ++k) {
    if (b_[k] >= 0) {
      int r = atomicAdd(&rcnt[b_[k]], 1);
      pairs[gbase[b_[k]] + r] = p_[k];
    }
  }
}

// k4: one block per bucket. LDS counting-sort by local dst, inject self-loops,
// emit ccol segment + start/end coalesced.
__global__ __launch_bounds__(256) void bucket_build(
    const unsigned int* __restrict__ pairs, const int* __restrict__ bucket_base,
    int* __restrict__ ccol, int* __restrict__ start, int* __restrict__ endp,
    int n) {
  __shared__ int cnt[256];
  __shared__ int ls[256];
  __shared__ int csave[256];
  __shared__ int part[256];
  __shared__ int sorted[SCAP];
  const int t = threadIdx.x;
  const int b = blockIdx.x;
  const int d0 = b << 8;
  const int DR = min(256, n - d0);
  const int in_base = bucket_base[b];
  const int nloc = bucket_base[b + 1] - in_base;
  const int out_base = in_base + d0;  // self-loops of earlier (full) buckets = d0

  cnt[t] = (t < DR) ? 1 : 0;  // 1 = self-loop
  __syncthreads();
  for (int i = t; i < nloc; i += 256)
    atomicAdd(&cnt[pairs[in_base + i] & 255u], 1);
  __syncthreads();
  int c = cnt[t];
  csave[t] = c;
  part[t] = c;
  __syncthreads();
#pragma unroll
  for (int off = 1; off < 256; off <<= 1) {
    int u = (t >= off) ? part[t - off] : 0;
    __syncthreads();
    part[t] += u;
    __syncthreads();
  }
  ls[t] = part[t] - c;  // exclusive local start
  __syncthreads();
  if (t < DR) {
    int s = out_base + ls[t];
    start[d0 + t] = s;
    endp[d0 + t] = s + csave[t];
    sorted[ls[t]] = d0 + t;  // self-loop src
    cnt[t] = 1;              // reuse as rank counter, slot 0 taken
  }
  __syncthreads();
  for (int i = t; i < nloc; i += 256) {
    unsigned int p = pairs[in_base + i];
    int j = (int)(p & 255u);
    int r = atomicAdd(&cnt[j], 1);
    int pos = ls[j] + r;
    if (pos < SCAP) sorted[pos] = (int)(p >> 8);
  }
  __syncthreads();
  int tot = nloc + DR;
  if (tot > SCAP) tot = SCAP;
  for (int i = t; i < tot; i += 256) ccol[out_base + i] = sorted[i];
}

// MFMA GEMM: h[n][64] = x[n][K] @ W[K][64], h stored fp16; per-head att dots.
// Block = 64 rows (4 waves x 16). W^T staged in LDS once (1 barrier); A
// fragments loaded directly global->register; K-loop fully unrolled, 0 barriers.
template <int K, bool XHALF>
__global__ __launch_bounds__(256) void gemm_mfma(
    const void* __restrict__ xin, const ushort* __restrict__ wt,
    const float* __restrict__ att_src, const float* __restrict__ att_dst,
    __half* __restrict__ h, float* __restrict__ as_, float* __restrict__ ad_,
    int n) {
  constexpr int WS = K + 8;           // wsh row stride (halfs); 2-way banks max
  __shared__ _Float16 wsh[64 * WS];   // W^T [col][k]
  const int tid = threadIdx.x;
  const int w = tid >> 6;
  const int lane = tid & 63;
  const int lr = lane & 15;   // A row / B col within tile
  const int kg = lane >> 4;   // k-group
  const int row0 = blockIdx.x * 64;

  {  // stage W^T once: 64*K halfs, coalesced ushort4
    const ushort4* src = (const ushort4*)wt;
    for (int i4 = tid; i4 < 64 * K / 4; i4 += 256) {
      int nr = i4 / (K / 4);
      int kc = i4 % (K / 4);
      *(ushort4*)&wsh[nr * WS + kc * 4] = src[i4];
    }
  }
  __syncthreads();  // the only barrier

  int rr = row0 + w * 16 + lr;
  if (rr > n - 1) rr = n - 1;  // tail rows duplicate row n-1; stores guarded

  f32x4 acc[4] = {};
#pragma unroll
  for (int ks = 0; ks < K; ks += 32) {
    f16x8 a;
    if constexpr (!XHALF) {
      const float* xp = (const float*)xin + (long long)rr * K + ks + kg * 8;
      float4 v0 = *(const float4*)xp;
      float4 v1 = *(const float4*)(xp + 4);
      a[0] = (_Float16)v0.x; a[1] = (_Float16)v0.y;
      a[2] = (_Float16)v0.z; a[3] = (_Float16)v0.w;
      a[4] = (_Float16)v1.x; a[5] = (_Float16)v1.y;
      a[6] = (_Float16)v1.z; a[7] = (_Float16)v1.w;
    } else {
      a = *(const f16x8*)((const ushort*)xin + (long long)rr * K + ks + kg * 8);
    }
#pragma unroll
    for (int ct = 0; ct < 4; ++ct) {
      f16x8 b = *(const f16x8*)&wsh[(ct * 16 + lr) * WS + ks + kg * 8];
      acc[ct] = __builtin_amdgcn_mfma_f32_16x16x32_f16(a, b, acc[ct], 0, 0, 0);
    }
  }

  // Epilogue: D[row=(lane>>4)*4+r][col=ct*16+lr]. h fp16 store + att dots
  // (head == col-tile ct); reduce over the 16 lanes holding a row.
  const int wrow = row0 + w * 16 + kg * 4;
#pragma unroll
  for (int ct = 0; ct < 4; ++ct) {
    const float as0 = att_src[ct * 16 + lr];
    const float ad0 = att_dst[ct * 16 + lr];
#pragma unroll
    for (int r = 0; r < 4; ++r) {
      const int row = wrow + r;
      const float v = acc[ct][r];
      if (row < n) h[(long long)row * 64 + ct * 16 + lr] = __float2half_rn(v);
      float s = v * as0, d = v * ad0;
      s += __shfl_xor(s, 1); s += __shfl_xor(s, 2);
      s += __shfl_xor(s, 4); s += __shfl_xor(s, 8);
      d += __shfl_xor(d, 1); d += __shfl_xor(d, 2);
      d += __shfl_xor(d, 4); d += __shfl_xor(d, 8);
      if (lr == 0 && row < n) {
        as_[row * 4 + ct] = s;
        ad_[row * 4 + ct] = d;
      }
    }
  }
}

// Half-wave (32 lanes) per dst node, 2 nodes/wave; lane covers 2 channels via
// __half2. mode 1: relu + fp16 out (layer-2 GEMM input); mode 0: f32 out.
__global__ __launch_bounds__(256) void node_agg_kernel(
    const int* __restrict__ ccol, const int* __restrict__ start,
    const int* __restrict__ endp,
    const float* __restrict__ as_, const float* __restrict__ ad_,
    const __half2* __restrict__ h2, const float* __restrict__ bias,
    float* __restrict__ fout, __half2* __restrict__ hout, int n, int mode) {
  const int node = blockIdx.x * 8 + (threadIdx.x >> 5);
  if (node >= n) return;
  const int hl = threadIdx.x & 31;  // half-lane: channels 2hl, 2hl+1
  const int hh = hl >> 3;           // head (8 half-lanes/head)
  const float adv = ad_[node * 4 + hh];
  const int s0i = start[node];
  const int d = endp[node] - s0i;
  const int* cp = ccol + s0i;
  float ax = 0.f, ay = 0.f, den = 0.f;
  int i = 0;
  for (; i + 4 <= d; i += 4) {  // 4x unroll for memory-level parallelism
    int s0 = cp[i], s1 = cp[i + 1], s2 = cp[i + 2], s3 = cp[i + 3];
    float p0 = __expf(lrelu(as_[s0 * 4 + hh] + adv));
    float p1 = __expf(lrelu(as_[s1 * 4 + hh] + adv));
    float p2 = __expf(lrelu(as_[s2 * 4 + hh] + adv));
    float p3 = __expf(lrelu(as_[s3 * 4 + hh] + adv));
    float2 h0 = __half22float2(h2[s0 * 32 + hl]);
    float2 h1 = __half22float2(h2[s1 * 32 + hl]);
    float2 h2v = __half22float2(h2[s2 * 32 + hl]);
    float2 h3 = __half22float2(h2[s3 * 32 + hl]);
    den += (p0 + p1) + (p2 + p3);
    ax = fmaf(p0, h0.x, ax); ay = fmaf(p0, h0.y, ay);
    ax = fmaf(p1, h1.x, ax); ay = fmaf(p1, h1.y, ay);
    ax = fmaf(p2, h2v.x, ax); ay = fmaf(p2, h2v.y, ay);
    ax = fmaf(p3, h3.x, ax); ay = fmaf(p3, h3.y, ay);
  }
  for (; i < d; ++i) {
    int s0 = cp[i];
    float p0 = __expf(lrelu(as_[s0 * 4 + hh] + adv));
    float2 h0 = __half22float2(h2[s0 * 32 + hl]);
    den += p0;
    ax = fmaf(p0, h0.x, ax); ay = fmaf(p0, h0.y, ay);
  }
  const float inv = 1.0f / (den + 1e-16f);
  float vx = ax * inv + bias[hl * 2];
  float vy = ay * inv + bias[hl * 2 + 1];
  if (mode == 1) {
    vx = fmaxf(vx, 0.f);
    vy = fmaxf(vy, 0.f);
    hout[node * 32 + hl] = __floats2half2_rn(vx, vy);
  } else {
    *(float2*)(fout + node * 64 + hl * 2) = make_float2(vx, vy);
  }
}

extern "C" void kernel_launch(void* const* d_in, const int* in_sizes, int n_in,
                              void* d_out, int out_size, void* d_ws, size_t ws_size,
                              hipStream_t stream) {
  const float* x = (const float*)d_in[0];
  const int* ei = (const int*)d_in[1];
  const float* W1 = (const float*)d_in[2];
  const float* att_s1 = (const float*)d_in[3];
  const float* att_d1 = (const float*)d_in[4];
  const float* b1 = (const float*)d_in[5];
  const float* W2 = (const float*)d_in[6];
  const float* att_s2 = (const float*)d_in[7];
  const float* att_d2 = (const float*)d_in[8];
  const float* b2 = (const float*)d_in[9];

  const int n = in_sizes[0] / 256;  // 100000
  const int E = in_sizes[1] / 2;    // 1600000
  const int* esrc = ei;
  const int* edst = ei + E;
  const int nbuck = (n + 255) >> 8;  // 391

  float* wsf = (float*)d_ws;
  __half* hbuf = (__half*)wsf;                  // [n*64] fp16 h (region: n*64 floats)
  float* xbuf = wsf + (long long)n * 64;        // [n*64] region; holds fp16 layer-2 input
  float* as_ = xbuf + (long long)n * 64;        // [n*4]
  float* ad_ = as_ + (long long)n * 4;          // [n*4]
  int* bucket_cnt = (int*)(ad_ + (long long)n * 4);  // [MAXB]
  int* bucket_base = bucket_cnt + MAXB;         // [MAXB+1]
  int* bucket_cursor = bucket_base + MAXB + 1;  // [MAXB]
  int* start = bucket_cursor + MAXB;            // [n]
  int* endp = start + n;                        // [n]
  unsigned int* pairs = (unsigned int*)(endp + n);  // [E]
  int* ccol = (int*)(pairs + E);                // [E+n]
  ushort* wt1 = (ushort*)(((uintptr_t)(ccol + E + n) + 15) & ~(uintptr_t)15);  // [64*256]
  ushort* wt2 = wt1 + 64 * 256;                 // [64*64]
  float* out = (float*)d_out;

  const int ebk = (E + CH - 1) / CH;  // 391 edge-chunk blocks
  const int gb = (n + 63) / 64;
  const int nb = (n + 7) / 8;  // 8 nodes per 256-thread block (2 per wave)

  // ---- prep: W -> W^T fp16 ----
  wprep_kernel<<<(256 * 64 + 255) / 256, 256, 0, stream>>>(W1, wt1, 256);
  wprep_kernel<<<(64 * 64 + 255) / 256, 256, 0, stream>>>(W2, wt2, 64);

  // ---- CSR bucket build (shared by both layers) ----
  ifill_kernel<<<(MAXB + 255) / 256, 256, 0, stream>>>(bucket_cnt, 0, MAXB);
  bucket_hist<<<ebk, 256, 0, stream>>>(edst, E, nbuck, bucket_cnt);
  bucket_scan<<<1, 512, 0, stream>>>(bucket_cnt, bucket_base, bucket_cursor, nbuck);
  place_kernel<<<ebk, 256, 0, stream>>>(esrc, edst, E, nbuck, bucket_cursor, pairs);
  bucket_build<<<nbuck, 256, 0, stream>>>(pairs, bucket_base, ccol, start, endp, n);

  // ---- layer 1 ----
  gemm_mfma<256, false><<<gb, 256, 0, stream>>>(x, wt1, att_s1, att_d1,
                                                hbuf, as_, ad_, n);
  node_agg_kernel<<<nb, 256, 0, stream>>>(ccol, start, endp, as_, ad_,
                                          (const __half2*)hbuf, b1,
                                          nullptr, (__half2*)xbuf, n, 1);

  // ---- layer 2 ----
  gemm_mfma<64, true><<<gb, 256, 0, stream>>>(xbuf, wt2, att_s2, att_d2,
                                              hbuf, as_, ad_, n);
  node_agg_kernel<<<nb, 256, 0, stream>>>(ccol, start, endp, as_, ad_,
                                          (const __half2*)hbuf, b2,
                                          out, nullptr, n, 0);
}